// Round 8
// baseline (250.523 us; speedup 1.0000x reference)
//
#include <hip/hip_runtime.h>
#include <cstddef>
#include <math.h>

// VQ layer: bf16 MFMA GEMM top-1, REGISTER-PIPELINED codebook (no LDS stage).
// R7 post-mortem: barriered LDS-chunk loop is structure-bound (~60us of 85us
// is stage->vmcnt->barrier serialization; halving all work R0->R1 moved dur
// only 100->88). chi is 256KB = L2/L1-resident, so LDS staging buys nothing:
// load A-tiles (16 codes x 32k per lane-slice) straight to registers,
// software-pipelined ONE TILE AHEAD via two named buffers (A*/B*). No
// s_barrier in the main loop; waves drift freely (16/CU); all 4 waves of a
// block read the IDENTICAL tile sequence -> L1 serves cross-wave re-reads.
// Compiler emits counted vmcnt for register loads (no drain-to-0: R3's trap
// was serial DMA->LDS->wait at 2 waves/SIMD; here 4 waves/SIMD + reg loads).
// acc = 2^21 + 2^20*(dot - 0.5*cnorm) (inputs pre-scaled by 1024);
// key = ((u32)acc<<10) + (1023 - quad*4 - T*16 - r), max-reduce (T=tile).
// Loss via moments: [Sum x^2 - 2 Sum dot + Sum cnt*cnorm]/(N*D); dot
// recovered from winning key. Epilogue = nt-store codebook gather.
// Separate k_final (R4: per-block __threadfence costs ~us on gfx950).

#define NROWS 131072
#define KC 1024
#define DD 128
#define NBLK 1024            // k_assign grid: 128 rows/block (4 waves x 32)

typedef __attribute__((ext_vector_type(8))) short short8;
typedef __attribute__((ext_vector_type(4))) float f32x4;
typedef __attribute__((ext_vector_type(4))) unsigned short u16x4;

struct WS {
  unsigned counts[KC];         // zeroed by k_prep
  float cnorm32[KC];
  double lossPart[NBLK];
  unsigned short chi[KC * DD]; // bf16 of (1024*c), plain row-major
};

static __device__ __forceinline__ unsigned short f2bf_rn(float f) {
  unsigned u = __float_as_uint(f);
  unsigned r = (u + 0x7FFFu + ((u >> 16) & 1u)) >> 16;  // RN-even
  return (unsigned short)r;
}

// prep: zero counts, bf16(1024*c) plain layout, fp32 cnorms.
__global__ __launch_bounds__(256) void k_prep(const float* __restrict__ cb,
                                              WS* __restrict__ ws) {
  int gid = blockIdx.x * 256 + threadIdx.x;   // 32768 threads
  if (gid < KC) ws->counts[gid] = 0u;
  int e0 = gid * 4;
  float4 c4 = *(const float4*)(cb + e0);
  float cf[4] = {c4.x, c4.y, c4.z, c4.w};
  u16x4 hv;
#pragma unroll
  for (int j = 0; j < 4; ++j) hv[j] = f2bf_rn(cf[j] * 1024.0f);
  *(u16x4*)&ws->chi[e0] = hv;
  if (gid < KC) {
    const float* cr = cb + (size_t)gid * DD;
    float a0 = 0, a1 = 0, a2 = 0, a3 = 0;
    for (int j = 0; j < DD; j += 4) {
      float4 v = *(const float4*)(cr + j);
      a0 = fmaf(v.x, v.x, a0);
      a1 = fmaf(v.y, v.y, a1);
      a2 = fmaf(v.z, v.z, a2);
      a3 = fmaf(v.w, v.w, a3);
    }
    ws->cnorm32[gid] = (a0 + a1) + (a2 + a3);
  }
}

// 4 waves/block; each wave owns 32 x-rows (Nf=2 resident B-frags);
// 64 code-tiles (16 codes each) stream through a 2-deep register pipeline.
__global__ __launch_bounds__(256, 4) void k_assign(
    const float* __restrict__ x, const float* __restrict__ cb,
    float* __restrict__ out, WS* __restrict__ ws) {
  __shared__ float cnsAll[KC];
  __shared__ unsigned sIdx[4][32];
  __shared__ double wsum[4];

  const int tid = threadIdx.x;
  const int wave = tid >> 6, lane = tid & 63;
  const int l15 = lane & 15, quad = lane >> 4;
  const int rowbase = blockIdx.x * 128 + wave * 32;

  for (int i = tid; i < KC; i += 256) cnsAll[i] = ws->cnorm32[i];

  // ---- resident B-fragments: x_hi scaled by 1024; free Sum x^2 ----
  short8 Bh[2][4];
  float xsq = 0.0f;
#pragma unroll
  for (int Nf = 0; Nf < 2; ++Nf) {
    const float* xr = x + (size_t)(rowbase + Nf * 16 + l15) * DD;
#pragma unroll
    for (int ks = 0; ks < 4; ++ks) {
      int k0 = ks * 32 + quad * 8;
      float4 u = *(const float4*)(xr + k0);
      float4 v = *(const float4*)(xr + k0 + 4);
      float f[8] = {u.x, u.y, u.z, u.w, v.x, v.y, v.z, v.w};
      short8 bh;
#pragma unroll
      for (int j = 0; j < 8; ++j) {
        xsq = fmaf(f[j], f[j], xsq);
        bh[j] = (short)f2bf_rn(f[j] * 1024.0f);
      }
      Bh[Nf][ks] = bh;
    }
  }

  unsigned k1[2] = {0u, 0u};
  // per-lane base into chi: row l15 of each tile, k-slice quad*8
  const unsigned short* chiL = ws->chi + (size_t)l15 * DD + quad * 8;

  short8 A0, A1, A2, A3, B0, B1, B2, B3;   // two named tile buffers

#define ISSUE_A(T) do {                                                      \
    const unsigned short* bp_ = chiL + (size_t)(T) * (16 * DD);              \
    A0 = *(const short8*)(bp_);       A1 = *(const short8*)(bp_ + 32);       \
    A2 = *(const short8*)(bp_ + 64);  A3 = *(const short8*)(bp_ + 96);       \
  } while (0)
#define ISSUE_B(T) do {                                                      \
    const unsigned short* bp_ = chiL + (size_t)(T) * (16 * DD);              \
    B0 = *(const short8*)(bp_);       B1 = *(const short8*)(bp_ + 32);       \
    B2 = *(const short8*)(bp_ + 64);  B3 = *(const short8*)(bp_ + 96);       \
  } while (0)
#define COMPUTE(T, C0, C1, C2, C3) do {                                      \
    f32x4 cn4_ = *(const f32x4*)&cnsAll[(T) * 16 + quad * 4];                \
    f32x4 ini_;                                                              \
    _Pragma("unroll")                                                        \
    for (int r_ = 0; r_ < 4; ++r_)                                           \
      ini_[r_] = fmaf(cn4_[r_], -524288.0f, 2097152.0f);                     \
    f32x4 ac0_ = ini_, ac1_ = ini_;                                          \
    __builtin_amdgcn_s_setprio(1);                                           \
    ac0_ = __builtin_amdgcn_mfma_f32_16x16x32_bf16(C0, Bh[0][0], ac0_, 0,0,0);\
    ac1_ = __builtin_amdgcn_mfma_f32_16x16x32_bf16(C0, Bh[1][0], ac1_, 0,0,0);\
    ac0_ = __builtin_amdgcn_mfma_f32_16x16x32_bf16(C1, Bh[0][1], ac0_, 0,0,0);\
    ac1_ = __builtin_amdgcn_mfma_f32_16x16x32_bf16(C1, Bh[1][1], ac1_, 0,0,0);\
    ac0_ = __builtin_amdgcn_mfma_f32_16x16x32_bf16(C2, Bh[0][2], ac0_, 0,0,0);\
    ac1_ = __builtin_amdgcn_mfma_f32_16x16x32_bf16(C2, Bh[1][2], ac1_, 0,0,0);\
    ac0_ = __builtin_amdgcn_mfma_f32_16x16x32_bf16(C3, Bh[0][3], ac0_, 0,0,0);\
    ac1_ = __builtin_amdgcn_mfma_f32_16x16x32_bf16(C3, Bh[1][3], ac1_, 0,0,0);\
    __builtin_amdgcn_s_setprio(0);                                           \
    const unsigned invqT_ = 1023u - (unsigned)(quad * 4) -                   \
                            (unsigned)((T) * 16);                            \
    _Pragma("unroll")                                                        \
    for (int r_ = 0; r_ < 4; ++r_) {                                         \
      unsigned q0_ = (unsigned)ac0_[r_];                                     \
      unsigned q1_ = (unsigned)ac1_[r_];                                     \
      k1[0] = max(k1[0], (q0_ << 10) + (invqT_ - (unsigned)r_));             \
      k1[1] = max(k1[1], (q1_ << 10) + (invqT_ - (unsigned)r_));             \
    }                                                                        \
  } while (0)

  ISSUE_A(0);
  ISSUE_B(1);
  // cnsAll ds_writes visible to all waves (loads above stay in flight)
  asm volatile("s_waitcnt lgkmcnt(0)" ::: "memory");
  __builtin_amdgcn_s_barrier();

  for (int p = 0; p < 31; ++p) {              // 64 tiles, 2-deep reg pipeline
    const int t0 = p * 2;
    COMPUTE(t0, A0, A1, A2, A3);
    ISSUE_A(t0 + 2);
    COMPUTE(t0 + 1, B0, B1, B2, B3);
    ISSUE_B(t0 + 3);
  }
  COMPUTE(62, A0, A1, A2, A3);
  COMPUTE(63, B0, B1, B2, B3);

#undef ISSUE_A
#undef ISSUE_B
#undef COMPUTE

  // ---- cross-quad argmax merge; idx + dot recovery (moment loss) ----
  float dsum = 0.0f;
#pragma unroll
  for (int Nf = 0; Nf < 2; ++Nf) {
    unsigned a1 = k1[Nf];
    a1 = max(a1, (unsigned)__shfl_xor((int)a1, 16));
    a1 = max(a1, (unsigned)__shfl_xor((int)a1, 32));
    if (quad == 0) {
      int idx = 1023 - (int)(a1 & 1023u);     // ties -> smallest index
      sIdx[wave][Nf * 16 + l15] = (unsigned)idx;
      atomicAdd(&ws->counts[idx], 1u);
      // acc = 2^21 + 2^20*(dot - 0.5*cn); q = floor(acc)
      float qf = (float)(a1 >> 10);
      dsum += (qf + 0.5f - 2097152.0f) * (1.0f / 1048576.0f) +
              0.5f * cnsAll[idx];
    }
  }

  // ---- epilogue: z_st = gathered fp32 codebook rows, nt stores ----
  const int rh = lane >> 5;                   // 0/1: two rows per iteration
  const int seg = lane & 31;
  for (int it = 0; it < 16; ++it) {
    int r = it * 2 + rh;
    unsigned idx = sIdx[wave][r];             // wave-synchronous LDS RAW
    f32x4 c4 = *(const f32x4*)(cb + (size_t)idx * DD + seg * 4);
    __builtin_nontemporal_store(
        c4, (f32x4*)(out + (size_t)(rowbase + r) * DD + seg * 4));
  }

  // ---- per-block moment partial: Sum x^2 - 2*Sum dot ----
  float v = fmaf(-2.0f, dsum, xsq);
  for (int off = 32; off; off >>= 1) v += __shfl_down(v, off);
  if (lane == 0) wsum[wave] = (double)v;
  __syncthreads();
  if (tid == 0)
    ws->lossPart[blockIdx.x] = wsum[0] + wsum[1] + wsum[2] + wsum[3];
}

__global__ __launch_bounds__(256) void k_final(float* __restrict__ out,
                                               WS* __restrict__ ws) {
  __shared__ double hs[256], ls[256];
  double h = 0.0, lp = 0.0;
  for (int i = threadIdx.x; i < KC; i += 256) {
    double p = (double)ws->counts[i] / (double)NROWS;
    h += p * log(p + 1e-10);
    lp += (double)ws->counts[i] * (double)ws->cnorm32[i];  // Sum cnt*cnorm
  }
  for (int i = threadIdx.x; i < NBLK; i += 256) lp += ws->lossPart[i];
  hs[threadIdx.x] = h;
  ls[threadIdx.x] = lp;
  __syncthreads();
  for (int off = 128; off; off >>= 1) {
    if ((int)threadIdx.x < off) {
      hs[threadIdx.x] += hs[threadIdx.x + off];
      ls[threadIdx.x] += ls[threadIdx.x + off];
    }
    __syncthreads();
  }
  if (threadIdx.x == 0) {
    double loss = ls[0] / (double)((size_t)NROWS * DD);
    out[16777216] = (float)loss;
    out[16777217] = (float)loss;
    out[16777218] = (float)exp(-hs[0]);
  }
}

extern "C" void kernel_launch(void* const* d_in, const int* in_sizes, int n_in,
                              void* d_out, int out_size, void* d_ws, size_t ws_size,
                              hipStream_t stream) {
  const float* x = (const float*)d_in[0];
  const float* cb = (const float*)d_in[1];
  float* out = (float*)d_out;
  WS* ws = (WS*)d_ws;

  k_prep<<<128, 256, 0, stream>>>(cb, ws);
  k_assign<<<NBLK, 256, 0, stream>>>(x, cb, out, ws);
  k_final<<<1, 256, 0, stream>>>(out, ws);
}

// Round 9
// 219.268 us; speedup vs baseline: 1.1425x; 1.1425x over previous
//
#include <hip/hip_runtime.h>
#include <cstddef>
#include <math.h>

// VQ layer: bf16 MFMA GEMM top-1, CODE-SPLIT + atomicMax merge.
// R5's proven chunk loop (stage DMA -> vmcnt(4) -> barrier -> MFMA -> barrier)
// kept verbatim; work split along the CODE axis: grid 2048, block (rowblk =
// bid>>1, half = bid&1) scans codes [half*512, +512) for 128 rows (8 chunks
// of 64). Partial argmins merge via atomicMax on the packed key (u32 max ==
// min dist, tie -> smaller global idx; key low-field = 1023 - global idx).
// Why: grid 2048 at 4 blocks/CU = two STAGGERED rounds -> round-2 prologues
// (x reads) overlap round-1 main loops; k_assign loses its epilogue (write
// burst) entirely. Paired bids read the same x rows ~simultaneously -> 2nd
// is an L3 hit. k_gather = dedicated streaming kernel (no LDS, full
// occupancy): bestKey -> gather cb -> nt-store out, recover dot + counts.
// Loss via moments: [Sum x^2 - 2 Sum dot + Sum cnt*cnorm]/(N*D).
//   Sum x^2 : k_assign half-0 blocks (x already in regs).
//   Sum dot : k_gather, from winning key q (trunc bias ~1e-8).
//   cnt*cn  : k_final.
// R4 lesson kept: no per-block __threadfence; kernel boundaries do the
// ordering. R8 lesson: no named-register pipelines (regalloc collapses
// them); LDS staging amortizes chi reads 4-way.

#define NROWS 131072
#define KC 1024
#define DD 128
#define NBLK 2048            // k_assign grid: (rowblk, half) pairs
#define NGB 1024             // k_gather grid: 128 rows/block

typedef __attribute__((ext_vector_type(8))) short short8;
typedef __attribute__((ext_vector_type(4))) float f32x4;
typedef __attribute__((ext_vector_type(4))) unsigned short u16x4;

struct WS {
  unsigned counts[KC];           // zeroed by k_prep
  float cnorm32[KC];
  unsigned bestKey[NROWS];       // zeroed by k_prep; atomicMax merge target
  double lossX[NGB];             // Sum x^2 partials (half-0 k_assign blocks)
  double lossD[NGB];             // Sum dot partials (k_gather blocks)
  unsigned short chi[KC * DD];   // bf16 of (1024*c), granule-swizzled
};

static __device__ __forceinline__ unsigned short f2bf_rn(float f) {
  unsigned u = __float_as_uint(f);
  unsigned r = (u + 0x7FFFu + ((u >> 16) & 1u)) >> 16;  // RN-even
  return (unsigned short)r;
}

// prep: zero counts+bestKey, bf16(1024*c) + granule-swizzle, fp32 cnorms.
__global__ __launch_bounds__(256) void k_prep(const float* __restrict__ cb,
                                              WS* __restrict__ ws) {
  int gid = blockIdx.x * 256 + threadIdx.x;   // 32768 threads
  if (gid < KC) ws->counts[gid] = 0u;
#pragma unroll
  for (int j = 0; j < 4; ++j) ws->bestKey[gid * 4 + j] = 0u;
  int e0 = gid * 4;
  int code = e0 >> 7, k = e0 & 127;
  int g = k >> 3, j0 = k & 7;                 // granule, sub-offset
  int gs = g ^ (code & 7);                    // swizzled granule position
  int dst = code * DD + gs * 8 + j0;
  float4 c4 = *(const float4*)(cb + e0);
  float cf[4] = {c4.x, c4.y, c4.z, c4.w};
  u16x4 hv;
#pragma unroll
  for (int j = 0; j < 4; ++j) hv[j] = f2bf_rn(cf[j] * 1024.0f);
  *(u16x4*)&ws->chi[dst] = hv;
  if (gid < KC) {
    const float* cr = cb + (size_t)gid * DD;
    float a0 = 0, a1 = 0, a2 = 0, a3 = 0;
    for (int j = 0; j < DD; j += 4) {
      float4 v = *(const float4*)(cr + j);
      a0 = fmaf(v.x, v.x, a0);
      a1 = fmaf(v.y, v.y, a1);
      a2 = fmaf(v.z, v.z, a2);
      a3 = fmaf(v.w, v.w, a3);
    }
    ws->cnorm32[gid] = (a0 + a1) + (a2 + a3);
  }
}

// 4 waves/block; wave owns 32 x-rows (Nf=2 resident B-frags); block scans
// a 512-code half through 8 double-buffered 64-code LDS chunks (R5 loop).
__global__ __launch_bounds__(256, 4) void k_assign(
    const float* __restrict__ x, const float* __restrict__ cb,
    float* __restrict__ out, WS* __restrict__ ws) {
  __shared__ __align__(16) unsigned short ldsC[2][64][128];  // [buf][code][k-swz]
  __shared__ float cns[512];
  __shared__ double wsum[4];

  const int tid = threadIdx.x;
  const int wave = tid >> 6, lane = tid & 63;
  const int l15 = lane & 15, quad = lane >> 4;
  const int rowblk = blockIdx.x >> 1, half = blockIdx.x & 1;
  const int cbase = half * 512;
  const int rowbase = rowblk * 128 + wave * 32;
  const int c0 = wave * 16;                   // 16 codes staged per wave

  // ---- prologue DMA: chunk 0 -> buf 0 (issued before anything else) ----
#pragma unroll
  for (int i = 0; i < 4; ++i) {
    const unsigned short* gp =
        ws->chi + (size_t)(cbase + c0 + i * 4) * DD + lane * 8;
    __builtin_amdgcn_global_load_lds(
        (const __attribute__((address_space(1))) unsigned int*)gp,
        (__attribute__((address_space(3))) unsigned int*)&ldsC[0][c0 + i * 4][0],
        16, 0, 0);
  }

  for (int i = tid; i < 512; i += 256) cns[i] = ws->cnorm32[cbase + i];

  // ---- resident B-fragments: x_hi scaled by 1024; free Sum x^2 ----
  short8 Bh[2][4];
  float xsq = 0.0f;
#pragma unroll
  for (int Nf = 0; Nf < 2; ++Nf) {
    const float* xr = x + (size_t)(rowbase + Nf * 16 + l15) * DD;
#pragma unroll
    for (int ks = 0; ks < 4; ++ks) {
      int k0 = ks * 32 + quad * 8;
      float4 u = *(const float4*)(xr + k0);
      float4 v = *(const float4*)(xr + k0 + 4);
      float f[8] = {u.x, u.y, u.z, u.w, v.x, v.y, v.z, v.w};
      short8 bh;
#pragma unroll
      for (int j = 0; j < 8; ++j) {
        xsq = fmaf(f[j], f[j], xsq);
        bh[j] = (short)f2bf_rn(f[j] * 1024.0f);
      }
      Bh[Nf][ks] = bh;
    }
  }

  unsigned k1[2] = {0u, 0u};
  const unsigned invq = 1023u - (unsigned)(quad * 4) - (unsigned)cbase;
  const int swz = l15 & 7;                    // read-side granule XOR

  // cns ds_writes visible to all waves; does NOT drain vmcnt (DMA flies on)
  asm volatile("s_waitcnt lgkmcnt(0)" ::: "memory");
  __builtin_amdgcn_s_barrier();
  asm volatile("" ::: "memory");

#pragma unroll 2
  for (int cc = 0; cc < 8; ++cc) {            // 8 chunks of 64 codes
    const int rb = cc & 1;
    const int nb = (cc + 1) & 1, nchunk = (cc + 1) & 7;  // cc=7 wraps (stray)
    // stage next chunk into the other buffer (protected by prev end-barrier)
#pragma unroll
    for (int i = 0; i < 4; ++i) {
      const unsigned short* gp =
          ws->chi + (size_t)(cbase + nchunk * 64 + c0 + i * 4) * DD + lane * 8;
      __builtin_amdgcn_global_load_lds(
          (const __attribute__((address_space(1))) unsigned int*)gp,
          (__attribute__((address_space(3))) unsigned int*)&ldsC[nb][c0 + i * 4][0],
          16, 0, 0);
    }
    // counted wait: <=4 outstanding == only the 4 just-issued -> cur chunk done
    asm volatile("s_waitcnt vmcnt(4)" ::: "memory");
    __builtin_amdgcn_s_barrier();             // all waves' cur-chunk DMA landed
    asm volatile("" ::: "memory");

    f32x4 acc[4][2];
#pragma unroll
    for (int Mf = 0; Mf < 4; ++Mf) {
      f32x4 cn4 = *(const f32x4*)&cns[cc * 64 + Mf * 16 + quad * 4];
      f32x4 ini;
#pragma unroll
      for (int r = 0; r < 4; ++r) ini[r] = fmaf(cn4[r], -524288.0f, 2097152.0f);
      acc[Mf][0] = ini; acc[Mf][1] = ini;
    }
    __builtin_amdgcn_s_setprio(1);            // favor MFMA-phase waves (T5)
#pragma unroll
    for (int ks = 0; ks < 4; ++ks) {
      const int goff = (((ks * 4 + quad) ^ swz) * 8);   // swizzled k-offset
      short8 Ah[4];
#pragma unroll
      for (int Mf = 0; Mf < 4; ++Mf)
        Ah[Mf] = *(const short8*)&ldsC[rb][Mf * 16 + l15][goff];
#pragma unroll
      for (int Mf = 0; Mf < 4; ++Mf)
#pragma unroll
        for (int Nf = 0; Nf < 2; ++Nf)
          acc[Mf][Nf] = __builtin_amdgcn_mfma_f32_16x16x32_bf16(
              Ah[Mf], Bh[Nf][ks], acc[Mf][Nf], 0, 0, 0);
    }
    __builtin_amdgcn_s_setprio(0);
    // ---- branch-free packed-key top-1 (GLOBAL slot in low field) ----
    const unsigned invqc = invq - (unsigned)(cc * 64);
#pragma unroll
    for (int Nf = 0; Nf < 2; ++Nf)
#pragma unroll
      for (int Mf = 0; Mf < 4; ++Mf)
#pragma unroll
        for (int r = 0; r < 4; ++r) {
          unsigned q = (unsigned)acc[Mf][Nf][r];          // truncating cvt
          unsigned pk = (q << 10) + (invqc - (unsigned)(Mf * 16 + r));
          k1[Nf] = max(k1[Nf], pk);
        }
    asm volatile("" ::: "memory");
    __builtin_amdgcn_s_barrier();             // readers done before next overwrite
    asm volatile("" ::: "memory");
  }
  // drain stray wrap-DMA before this block's LDS can be reallocated
  asm volatile("s_waitcnt vmcnt(0)" ::: "memory");

  // ---- cross-quad argmax merge; publish via device atomicMax ----
#pragma unroll
  for (int Nf = 0; Nf < 2; ++Nf) {
    unsigned a1 = k1[Nf];
    a1 = max(a1, (unsigned)__shfl_xor((int)a1, 16));
    a1 = max(a1, (unsigned)__shfl_xor((int)a1, 32));
    if (quad == 0)
      atomicMax(&ws->bestKey[rowbase + Nf * 16 + l15], a1);
  }

  // ---- Sum x^2 partial (once per rowblk: half-0 blocks only) ----
  float v = xsq;
  for (int off = 32; off; off >>= 1) v += __shfl_down(v, off);
  if (lane == 0) wsum[wave] = (double)v;
  __syncthreads();
  if (tid == 0 && half == 0)
    ws->lossX[rowblk] = wsum[0] + wsum[1] + wsum[2] + wsum[3];
}

// streaming gather: bestKey -> idx; out = cb row (nt); recover dot; counts.
__global__ __launch_bounds__(256) void k_gather(
    const float* __restrict__ cb, float* __restrict__ out,
    WS* __restrict__ ws) {
  __shared__ double wsum[4];
  const int tid = threadIdx.x;
  const int wave = tid >> 6, lane = tid & 63;
  const int rh = lane >> 5, seg = lane & 31;
  const int rowbase = blockIdx.x * 128 + wave * 32;

  float dsum = 0.0f;
  for (int it = 0; it < 16; ++it) {
    int r = it * 2 + rh;
    int row = rowbase + r;
    unsigned key = ws->bestKey[row];
    unsigned idx = 1023u - (key & 1023u);
    f32x4 c4 = *(const f32x4*)(cb + (size_t)idx * DD + seg * 4);
    __builtin_nontemporal_store(
        c4, (f32x4*)(out + (size_t)row * DD + seg * 4));
    if (seg == 0) {
      atomicAdd(&ws->counts[idx], 1u);
      // acc = 2^21 + 2^20*(dot - 0.5*cn); q = floor(acc)
      float qf = (float)(key >> 10);
      dsum += (qf + 0.5f - 2097152.0f) * (1.0f / 1048576.0f) +
              0.5f * ws->cnorm32[idx];
    }
  }
  for (int off = 32; off; off >>= 1) dsum += __shfl_down(dsum, off);
  if (lane == 0) wsum[wave] = (double)dsum;
  __syncthreads();
  if (tid == 0)
    ws->lossD[blockIdx.x] = wsum[0] + wsum[1] + wsum[2] + wsum[3];
}

__global__ __launch_bounds__(256) void k_final(float* __restrict__ out,
                                               WS* __restrict__ ws) {
  __shared__ double hs[256], ls[256];
  double h = 0.0, lp = 0.0;
  for (int i = threadIdx.x; i < KC; i += 256) {
    double p = (double)ws->counts[i] / (double)NROWS;
    h += p * log(p + 1e-10);
    lp += (double)ws->counts[i] * (double)ws->cnorm32[i];  // Sum cnt*cnorm
  }
  for (int i = threadIdx.x; i < NGB; i += 256)
    lp += ws->lossX[i] - 2.0 * ws->lossD[i];
  hs[threadIdx.x] = h;
  ls[threadIdx.x] = lp;
  __syncthreads();
  for (int off = 128; off; off >>= 1) {
    if ((int)threadIdx.x < off) {
      hs[threadIdx.x] += hs[threadIdx.x + off];
      ls[threadIdx.x] += ls[threadIdx.x + off];
    }
    __syncthreads();
  }
  if (threadIdx.x == 0) {
    double loss = ls[0] / (double)((size_t)NROWS * DD);
    out[16777216] = (float)loss;
    out[16777217] = (float)loss;
    out[16777218] = (float)exp(-hs[0]);
  }
}

extern "C" void kernel_launch(void* const* d_in, const int* in_sizes, int n_in,
                              void* d_out, int out_size, void* d_ws, size_t ws_size,
                              hipStream_t stream) {
  const float* x = (const float*)d_in[0];
  const float* cb = (const float*)d_in[1];
  float* out = (float*)d_out;
  WS* ws = (WS*)d_ws;

  k_prep<<<128, 256, 0, stream>>>(cb, ws);
  k_assign<<<NBLK, 256, 0, stream>>>(x, cb, out, ws);
  k_gather<<<NGB, 256, 0, stream>>>(cb, out, ws);
  k_final<<<1, 256, 0, stream>>>(out, ws);
}